// Round 5
// baseline (1498.200 us; speedup 1.0000x reference)
//
#include <hip/hip_runtime.h>
#include <hip/hip_bf16.h>
#include <stdint.h>

#define NB 8
#define NS 256
#define NH 512
#define NG 1024
#define NV 256
#define NL 24
#define NC 320
#define NT 2048
#define EPSF 1e-5f

typedef __bf16 bf16;
typedef bf16 bf16x8 __attribute__((ext_vector_type(8)));
typedef float f32x4 __attribute__((ext_vector_type(4)));

__device__ __forceinline__ bf16 f2bf(float f) {
    uint32_t u = __builtin_bit_cast(uint32_t, f);
    u += 0x7FFFu + ((u >> 16) & 1u);
    uint16_t b = (uint16_t)(u >> 16);
    return __builtin_bit_cast(bf16, b);
}

// async global->LDS, 16B per lane; lds dst = wave-uniform base + lane*16B
__device__ __forceinline__ void gload16(const void* g, void* l) {
    __builtin_amdgcn_global_load_lds(
        (const __attribute__((address_space(1))) void*)g,
        (__attribute__((address_space(3))) void*)l,
        16, 0, 0);
}

// ---- stage one 64-row x 64-elem bf16 tile (row stride ldk elems) into LDS.
// LDS layout: row*128B, chunk(16B) XOR-swizzled by (row&7).  Source chunk is
// pre-swizzled so the gload dest stays linear (both-sides-or-neither rule).
__device__ __forceinline__ void stage64(
    const bf16* __restrict__ src, int ldk, bf16* lds, int wv_, int lane)
{
    #pragma unroll
    for (int j = 0; j < 2; ++j) {
        const int gI = wv_*2 + j;
        const int r  = gI*8 + (lane >> 3);
        const int ch = (lane & 7) ^ (lane >> 3);   // (lane>>3) == r&7
        gload16(src + (size_t)r*ldk + ch*8, lds + gI*512);
    }
}
// swizzled fragment read: row in [0,64), ch = 16B-chunk in [0,8)
__device__ __forceinline__ const bf16x8* fragp(const bf16* lds, int row, int ch) {
    return (const bf16x8*)(lds + row*64 + ((ch ^ (row & 7)) << 3));
}

#define MFMA(a,b,c) __builtin_amdgcn_mfma_f32_16x16x32_bf16(a, b, c, 0, 0, 0)

// ---------------- f32 -> bf16 bulk convert (n8 = elems/8)
__global__ __launch_bounds__(256) void k_cvt(
    const float* __restrict__ src, bf16* __restrict__ dst, int n8)
{
    int i = blockIdx.x*256 + threadIdx.x;
    const int stride = gridDim.x*256;
    for (; i < n8; i += stride) {
        const float* s = src + (size_t)i*8;
        bf16x8 t;
        #pragma unroll
        for (int j = 0; j < 8; ++j) t[j] = f2bf(s[j]);
        *(bf16x8*)&dst[(size_t)i*8] = t;
    }
}

// ---------------- x[b][c][s] f32 -> xT[b*256+s][c] bf16 (64x64 LDS transpose)
__global__ __launch_bounds__(256) void k_trx(
    const float* __restrict__ x, bf16* __restrict__ xT)
{
    __shared__ bf16 Ls[64*72];
    const int s0 = blockIdx.x*64, c0 = blockIdx.y*64, b = blockIdx.z;
    const int tid = threadIdx.x;
    #pragma unroll
    for (int e = 0; e < 16; ++e) {
        int idx = tid + e*256;
        int c = idx >> 6, s = idx & 63;
        Ls[s*72 + c] = f2bf(x[(size_t)(b*NC + c0 + c)*NS + s0 + s]);
    }
    __syncthreads();
    #pragma unroll
    for (int e = 0; e < 2; ++e) {
        int idx = tid + e*256;
        int s = idx >> 3, ch = idx & 7;
        *(bf16x8*)&xT[(size_t)(b*NS + s0 + s)*NC + c0 + ch*8] =
            *(const bf16x8*)&Ls[s*72 + ch*8];
    }
}

// ---------------- stem GEMM: h[t,o] = xT[t,:] . wb[o,:]; + ss for rl[0]
__global__ __launch_bounds__(256) void k_stem_b(
    const bf16* __restrict__ xT, const bf16* __restrict__ wb,
    float* __restrict__ h, float* __restrict__ ss_out)
{
    __shared__ __align__(16) bf16 As[2][4096], Bs[2][4096];
    __shared__ float Cs[64*66];
    const int t0 = blockIdx.x*64, n0 = blockIdx.y*64;
    const int tid = threadIdx.x, lane = tid & 63, wv_ = tid >> 6;
    const int wm = wv_ >> 1, wn = wv_ & 1;
    const int fr = lane & 15, kq = lane >> 4;
    const bf16* Ag = xT + (size_t)t0*NC;
    const bf16* Bg = wb + (size_t)n0*NC;
    f32x4 acc[2][2] = {};
    stage64(Ag, NC, As[0], wv_, lane);
    stage64(Bg, NC, Bs[0], wv_, lane);
    __syncthreads();
    const int NIT = NC/64;
    for (int it = 0; it < NIT; ++it) {
        const int cur = it & 1;
        if (it + 1 < NIT) {
            stage64(Ag + (it+1)*64, NC, As[cur^1], wv_, lane);
            stage64(Bg + (it+1)*64, NC, Bs[cur^1], wv_, lane);
        }
        #pragma unroll
        for (int kk = 0; kk < 2; ++kk) {
            const int ch = kk*4 + kq;
            bf16x8 a0 = *fragp(As[cur], wm*32 + fr,      ch);
            bf16x8 a1 = *fragp(As[cur], wm*32 + 16 + fr, ch);
            bf16x8 b0 = *fragp(Bs[cur], wn*32 + fr,      ch);
            bf16x8 b1 = *fragp(Bs[cur], wn*32 + 16 + fr, ch);
            acc[0][0] = MFMA(a0, b0, acc[0][0]);
            acc[0][1] = MFMA(a0, b1, acc[0][1]);
            acc[1][0] = MFMA(a1, b0, acc[1][0]);
            acc[1][1] = MFMA(a1, b1, acc[1][1]);
        }
        __syncthreads();
    }
    const int row4 = (lane >> 4)*4, col = lane & 15;
    #pragma unroll
    for (int mi = 0; mi < 2; ++mi)
      #pragma unroll
      for (int ni = 0; ni < 2; ++ni)
        #pragma unroll
        for (int r = 0; r < 4; ++r)
            Cs[(wm*32 + mi*16 + row4 + r)*66 + wn*32 + ni*16 + col] = acc[mi][ni][r];
    __syncthreads();
    const int rr = tid >> 2, c16 = (tid & 3)*16;
    float ssum = 0.f;
    float* dst = &h[(size_t)(t0 + rr)*NH + n0 + c16];
    #pragma unroll
    for (int i = 0; i < 16; ++i) {
        float v = Cs[rr*66 + c16 + i];
        dst[i] = v;
        ssum += v*v;
    }
    ssum += __shfl_xor(ssum, 1, 64);
    ssum += __shfl_xor(ssum, 2, 64);
    if ((tid & 3) == 0) atomicAdd(&ss_out[t0 + rr], ssum);
}

// ---------------- unified local/global mix (round-3 verified)
template<int STR>
__global__ __launch_bounds__(256) void k_mix(
    float* __restrict__ h, const float* __restrict__ ss_in,
    const float* __restrict__ w, const float* __restrict__ rmsw,
    const float* __restrict__ alpha_p, float* __restrict__ ss_out)
{
    __shared__ float raw[16*64];
    __shared__ float rstdL[16];
    const int b = blockIdx.x >> 4, g = blockIdx.x & 15, c0 = blockIdx.y*64;
    const int tid = threadIdx.x;
    const int c = tid & 63, pq = tid >> 6;
    const int base = b*NS + (STR == 1 ? g*16 : g);
    if (tid < 16) rstdL[tid] = rsqrtf(ss_in[base + tid*STR]*(1.f/NH) + EPSF);
    #pragma unroll
    for (int e = 0; e < 4; ++e) {
        int idx = tid + e*256;
        int j = idx >> 6, cc = idx & 63;
        raw[j*64 + cc] = h[(size_t)(base + j*STR)*NH + c0 + cc];
    }
    __syncthreads();
    float u[16];
    #pragma unroll
    for (int j = 0; j < 16; ++j) u[j] = raw[j*64 + c] * rstdL[j];
    const float al = *alpha_p;
    const float rc = rmsw[c0 + c] * al;
    const float* wrow = &w[(size_t)(c0 + c)*256 + pq*64];
    float hn[4];
    #pragma unroll
    for (int q = 0; q < 4; ++q) {
        float acc = 0.f;
        #pragma unroll
        for (int jv = 0; jv < 4; ++jv) {
            float4 w4 = *(const float4*)&wrow[q*16 + jv*4];
            acc += w4.x*u[jv*4+0] + w4.y*u[jv*4+1] + w4.z*u[jv*4+2] + w4.w*u[jv*4+3];
        }
        const int p = pq*4 + q;
        hn[q] = raw[p*64 + c] + rc*acc;
        h[(size_t)(base + p*STR)*NH + c0 + c] = hn[q];
    }
    #pragma unroll
    for (int q = 0; q < 4; ++q) {
        float ssum = hn[q]*hn[q];
        ssum += __shfl_xor(ssum, 1, 64);
        ssum += __shfl_xor(ssum, 2, 64);
        ssum += __shfl_xor(ssum, 4, 64);
        ssum += __shfl_xor(ssum, 8, 64);
        ssum += __shfl_xor(ssum, 16, 64);
        ssum += __shfl_xor(ssum, 32, 64);
        if (c == 0) atomicAdd(&ss_out[base + (pq*4 + q)*STR], ssum);
    }
}

// ---------------- norm: a[t,c] = bf16( h[t,c] * rstd(t) * rmsw[c] )
__global__ __launch_bounds__(256) void k_norm(
    const float* __restrict__ h, const float* __restrict__ ss_in,
    const float* __restrict__ rmsw, bf16* __restrict__ a)
{
    const int t = blockIdx.x*4 + (threadIdx.x >> 6);
    const int c8 = (threadIdx.x & 63)*8;
    const float rstd = rsqrtf(ss_in[t]*(1.f/NH) + EPSF);
    const float* src = &h[(size_t)t*NH + c8];
    float4 h0 = *(const float4*)&src[0];
    float4 h1 = *(const float4*)&src[4];
    float4 w0 = *(const float4*)&rmsw[c8];
    float4 w1 = *(const float4*)&rmsw[c8 + 4];
    bf16x8 o;
    o[0] = f2bf(h0.x*rstd*w0.x); o[1] = f2bf(h0.y*rstd*w0.y);
    o[2] = f2bf(h0.z*rstd*w0.z); o[3] = f2bf(h0.w*rstd*w0.w);
    o[4] = f2bf(h1.x*rstd*w1.x); o[5] = f2bf(h1.y*rstd*w1.y);
    o[6] = f2bf(h1.z*rstd*w1.z); o[7] = f2bf(h1.w*rstd*w1.w);
    *(bf16x8*)&a[(size_t)t*NH + c8] = o;
}

// ---------------- mlp in: g = silu(wv . a) * (wg . a)   (bf16 out)
__global__ __launch_bounds__(256) void k_mlp_in(
    const bf16* __restrict__ a, const bf16* __restrict__ wvl,
    const bf16* __restrict__ wgl, bf16* __restrict__ g)
{
    __shared__ __align__(16) bf16 As[2][4096], B1s[2][4096], B3s[2][4096];
    __shared__ bf16 Gs[64*72];
    const int t0 = blockIdx.x*64, n0 = blockIdx.y*64;
    const int tid = threadIdx.x, lane = tid & 63, wv_ = tid >> 6;
    const int wm = wv_ >> 1, wn = wv_ & 1;
    const int fr = lane & 15, kq = lane >> 4;
    const bf16* Ag = a   + (size_t)t0*NH;
    const bf16* Vg = wvl + (size_t)n0*NH;
    const bf16* Gg = wgl + (size_t)n0*NH;
    f32x4 acc1[2][2] = {}, acc3[2][2] = {};
    stage64(Ag, NH, As[0],  wv_, lane);
    stage64(Vg, NH, B1s[0], wv_, lane);
    stage64(Gg, NH, B3s[0], wv_, lane);
    __syncthreads();
    const int NIT = NH/64;
    for (int it = 0; it < NIT; ++it) {
        const int cur = it & 1;
        if (it + 1 < NIT) {
            stage64(Ag + (it+1)*64, NH, As[cur^1],  wv_, lane);
            stage64(Vg + (it+1)*64, NH, B1s[cur^1], wv_, lane);
            stage64(Gg + (it+1)*64, NH, B3s[cur^1], wv_, lane);
        }
        #pragma unroll
        for (int kk = 0; kk < 2; ++kk) {
            const int ch = kk*4 + kq;
            bf16x8 a0 = *fragp(As[cur],  wm*32 + fr,      ch);
            bf16x8 a1 = *fragp(As[cur],  wm*32 + 16 + fr, ch);
            bf16x8 u0 = *fragp(B1s[cur], wn*32 + fr,      ch);
            bf16x8 u1 = *fragp(B1s[cur], wn*32 + 16 + fr, ch);
            bf16x8 v0 = *fragp(B3s[cur], wn*32 + fr,      ch);
            bf16x8 v1 = *fragp(B3s[cur], wn*32 + 16 + fr, ch);
            acc1[0][0] = MFMA(a0, u0, acc1[0][0]);
            acc1[0][1] = MFMA(a0, u1, acc1[0][1]);
            acc1[1][0] = MFMA(a1, u0, acc1[1][0]);
            acc1[1][1] = MFMA(a1, u1, acc1[1][1]);
            acc3[0][0] = MFMA(a0, v0, acc3[0][0]);
            acc3[0][1] = MFMA(a0, v1, acc3[0][1]);
            acc3[1][0] = MFMA(a1, v0, acc3[1][0]);
            acc3[1][1] = MFMA(a1, v1, acc3[1][1]);
        }
        __syncthreads();
    }
    const int row4 = (lane >> 4)*4, col = lane & 15;
    #pragma unroll
    for (int mi = 0; mi < 2; ++mi)
      #pragma unroll
      for (int ni = 0; ni < 2; ++ni)
        #pragma unroll
        for (int r = 0; r < 4; ++r) {
            float xv = acc1[mi][ni][r];
            float gl = (xv / (1.f + __expf(-xv))) * acc3[mi][ni][r];
            Gs[(wm*32 + mi*16 + row4 + r)*72 + wn*32 + ni*16 + col] = f2bf(gl);
        }
    __syncthreads();
    const int rr = tid >> 2, c16 = (tid & 3)*16;
    bf16x8 o0 = *(const bf16x8*)&Gs[rr*72 + c16];
    bf16x8 o1 = *(const bf16x8*)&Gs[rr*72 + c16 + 8];
    *(bf16x8*)&g[(size_t)(t0 + rr)*NG + n0 + c16] = o0;
    *(bf16x8*)&g[(size_t)(t0 + rr)*NG + n0 + c16 + 8] = o1;
}

// ---------------- mlp out: h += alpha * (wo . g); + ss for next norm
__global__ __launch_bounds__(256) void k_mlp_out(
    const bf16* __restrict__ g, const bf16* __restrict__ wol,
    const float* __restrict__ alpha_p, float* __restrict__ h,
    float* __restrict__ ss_out)
{
    __shared__ __align__(16) bf16 As[2][4096], Bs[2][4096];
    __shared__ float Cs[64*66];
    const int t0 = blockIdx.x*64, n0 = blockIdx.y*64;
    const int tid = threadIdx.x, lane = tid & 63, wv_ = tid >> 6;
    const int wm = wv_ >> 1, wn = wv_ & 1;
    const int fr = lane & 15, kq = lane >> 4;
    const bf16* Ag = g   + (size_t)t0*NG;
    const bf16* Bg = wol + (size_t)n0*NG;
    f32x4 acc[2][2] = {};
    stage64(Ag, NG, As[0], wv_, lane);
    stage64(Bg, NG, Bs[0], wv_, lane);
    __syncthreads();
    const int NIT = NG/64;
    for (int it = 0; it < NIT; ++it) {
        const int cur = it & 1;
        if (it + 1 < NIT) {
            stage64(Ag + (it+1)*64, NG, As[cur^1], wv_, lane);
            stage64(Bg + (it+1)*64, NG, Bs[cur^1], wv_, lane);
        }
        #pragma unroll
        for (int kk = 0; kk < 2; ++kk) {
            const int ch = kk*4 + kq;
            bf16x8 a0 = *fragp(As[cur], wm*32 + fr,      ch);
            bf16x8 a1 = *fragp(As[cur], wm*32 + 16 + fr, ch);
            bf16x8 b0 = *fragp(Bs[cur], wn*32 + fr,      ch);
            bf16x8 b1 = *fragp(Bs[cur], wn*32 + 16 + fr, ch);
            acc[0][0] = MFMA(a0, b0, acc[0][0]);
            acc[0][1] = MFMA(a0, b1, acc[0][1]);
            acc[1][0] = MFMA(a1, b0, acc[1][0]);
            acc[1][1] = MFMA(a1, b1, acc[1][1]);
        }
        __syncthreads();
    }
    const int row4 = (lane >> 4)*4, col = lane & 15;
    #pragma unroll
    for (int mi = 0; mi < 2; ++mi)
      #pragma unroll
      for (int ni = 0; ni < 2; ++ni)
        #pragma unroll
        for (int r = 0; r < 4; ++r)
            Cs[(wm*32 + mi*16 + row4 + r)*66 + wn*32 + ni*16 + col] = acc[mi][ni][r];
    __syncthreads();
    const float am = *alpha_p;
    const int rr = tid >> 2, c16 = (tid & 3)*16;
    float* dst = &h[(size_t)(t0 + rr)*NH + n0 + c16];
    float ssum = 0.f;
    #pragma unroll
    for (int i = 0; i < 16; ++i) {
        float hn = dst[i] + am * Cs[rr*66 + c16 + i];
        dst[i] = hn;
        ssum += hn*hn;
    }
    ssum += __shfl_xor(ssum, 1, 64);
    ssum += __shfl_xor(ssum, 2, 64);
    if ((tid & 3) == 0) atomicAdd(&ss_out[t0 + rr], ssum);
}

// ---------------- head: logits = scale * head_w . a   (a pre-normed w/ head_rms)
__global__ __launch_bounds__(256) void k_head(
    const bf16* __restrict__ a, const bf16* __restrict__ hw,
    const float* __restrict__ scale_p, float* __restrict__ out)
{
    __shared__ __align__(16) bf16 As[2][4096], Bs[2][4096];
    __shared__ float Ls[64*66];
    const int t0 = blockIdx.x*64, n0 = blockIdx.y*64;
    const int tid = threadIdx.x, lane = tid & 63, wv_ = tid >> 6;
    const int wm = wv_ >> 1, wn = wv_ & 1;
    const int fr = lane & 15, kq = lane >> 4;
    const bf16* Ag = a  + (size_t)t0*NH;
    const bf16* Bg = hw + (size_t)n0*NH;
    f32x4 acc[2][2] = {};
    stage64(Ag, NH, As[0], wv_, lane);
    stage64(Bg, NH, Bs[0], wv_, lane);
    __syncthreads();
    const int NIT = NH/64;
    for (int it = 0; it < NIT; ++it) {
        const int cur = it & 1;
        if (it + 1 < NIT) {
            stage64(Ag + (it+1)*64, NH, As[cur^1], wv_, lane);
            stage64(Bg + (it+1)*64, NH, Bs[cur^1], wv_, lane);
        }
        #pragma unroll
        for (int kk = 0; kk < 2; ++kk) {
            const int ch = kk*4 + kq;
            bf16x8 a0 = *fragp(As[cur], wm*32 + fr,      ch);
            bf16x8 a1 = *fragp(As[cur], wm*32 + 16 + fr, ch);
            bf16x8 b0 = *fragp(Bs[cur], wn*32 + fr,      ch);
            bf16x8 b1 = *fragp(Bs[cur], wn*32 + 16 + fr, ch);
            acc[0][0] = MFMA(a0, b0, acc[0][0]);
            acc[0][1] = MFMA(a0, b1, acc[0][1]);
            acc[1][0] = MFMA(a1, b0, acc[1][0]);
            acc[1][1] = MFMA(a1, b1, acc[1][1]);
        }
        __syncthreads();
    }
    const float sc = *scale_p;
    const int row4 = (lane >> 4)*4, col = lane & 15;
    #pragma unroll
    for (int mi = 0; mi < 2; ++mi)
      #pragma unroll
      for (int ni = 0; ni < 2; ++ni)
        #pragma unroll
        for (int r = 0; r < 4; ++r)
            Ls[(wm*32 + mi*16 + row4 + r)*66 + wn*32 + ni*16 + col] = sc * acc[mi][ni][r];
    __syncthreads();
    const int vv = tid >> 2, s16 = (tid & 3)*16;
    const int b = t0 >> 8, s0 = t0 & 255;
    float* dst = &out[((size_t)(b*NV + n0 + vv))*NS + s0 + s16];
    #pragma unroll
    for (int i = 0; i < 16; ++i) dst[i] = Ls[(s16 + i)*66 + vv];
}

extern "C" void kernel_launch(void* const* d_in, const int* in_sizes, int n_in,
                              void* d_out, int out_size, void* d_ws, size_t ws_size,
                              hipStream_t stream) {
    const float* x          = (const float*)d_in[0];
    const float* stem_w     = (const float*)d_in[1];
    const float* rms_local  = (const float*)d_in[2];
    const float* rms_global = (const float*)d_in[3];
    const float* rms_ffn    = (const float*)d_in[4];
    const float* alpha_local  = (const float*)d_in[5];
    const float* alpha_global = (const float*)d_in[6];
    const float* alpha_mlp    = (const float*)d_in[7];
    const float* w_local    = (const float*)d_in[8];
    const float* w_global   = (const float*)d_in[9];
    const float* wv         = (const float*)d_in[10];
    const float* wg         = (const float*)d_in[11];
    const float* wo         = (const float*)d_in[12];
    const float* head_rms   = (const float*)d_in[13];
    const float* head_scale = (const float*)d_in[14];
    const float* head_w     = (const float*)d_in[15];
    float* out = (float*)d_out;

    char* ws = (char*)d_ws;
    const size_t MB = 1024*1024;
    float* h    = (float*)(ws);                 // [0,4MB)
    bf16*  g    = (bf16*)(ws + 4*MB);           // [4,8MB)
    bf16*  a_bf = (bf16*)(ws + 8*MB);           // [8,10MB)
    float* ss   = (float*)(ws + 10*MB);         // 73*2048*4 = 584KB
    float* ss_rl = ss;
    float* ss_rg = ss + 24*NT;
    float* ss_rf = ss + 48*NT;
    float* ss_hd = ss + 72*NT;

    bf16* xT      = (bf16*)(ws + 16*MB);        // 1.31MB
    bf16* stem_wb = (bf16*)(ws + 18*MB);        // 0.33MB
    bf16* head_wb = (bf16*)(ws + 19*MB);        // 0.26MB
    bf16* wv_b    = (bf16*)(ws + 20*MB);        // 24MB (pre) / 1MB slab (!pre)
    bf16* wg_b    = (bf16*)(ws + 44*MB);
    bf16* wo_b    = (bf16*)(ws + 68*MB);
    const bool pre = ws_size >= 92*MB;
    // fallback per-layer slabs (only if ws is small; needs >= 23MB)
    bf16* lwv = (bf16*)(ws + 20*MB);
    bf16* lwg = (bf16*)(ws + 21*MB);
    bf16* lwo = (bf16*)(ws + 22*MB);

    hipMemsetAsync(ss, 0, (size_t)73*NT*sizeof(float), stream);

    k_cvt<<<80, 256, 0, stream>>>(stem_w, stem_wb, NH*NC/8);
    k_cvt<<<64, 256, 0, stream>>>(head_w, head_wb, NV*NH/8);
    k_trx<<<dim3(4, 5, 8), 256, 0, stream>>>(x, xT);
    if (pre) {
        k_cvt<<<2048, 256, 0, stream>>>(wv, wv_b, NL*NG*NH/8);
        k_cvt<<<2048, 256, 0, stream>>>(wg, wg_b, NL*NG*NH/8);
        k_cvt<<<2048, 256, 0, stream>>>(wo, wo_b, NL*NH*NG/8);
    }
    k_stem_b<<<dim3(32, 8), 256, 0, stream>>>(xT, stem_wb, h, ss_rl);

    for (int l = 0; l < NL; ++l) {
        k_mix<1><<<dim3(128, 8), 256, 0, stream>>>(
            h, ss_rl + l*NT, w_local + (size_t)l*NH*256,
            rms_local + l*NH, alpha_local + l, ss_rg + l*NT);
        k_mix<16><<<dim3(128, 8), 256, 0, stream>>>(
            h, ss_rg + l*NT, w_global + (size_t)l*NH*256,
            rms_global + l*NH, alpha_global + l, ss_rf + l*NT);
        k_norm<<<512, 256, 0, stream>>>(h, ss_rf + l*NT, rms_ffn + l*NH, a_bf);
        float* ssn = (l == NL-1) ? ss_hd : (ss_rl + (l+1)*NT);
        const bf16 *pwv, *pwg, *pwo;
        if (pre) {
            pwv = wv_b + (size_t)l*NG*NH;
            pwg = wg_b + (size_t)l*NG*NH;
            pwo = wo_b + (size_t)l*NH*NG;
        } else {
            k_cvt<<<512, 256, 0, stream>>>(wv + (size_t)l*NG*NH, lwv, NG*NH/8);
            k_cvt<<<512, 256, 0, stream>>>(wg + (size_t)l*NG*NH, lwg, NG*NH/8);
            k_cvt<<<512, 256, 0, stream>>>(wo + (size_t)l*NH*NG, lwo, NH*NG/8);
            pwv = lwv; pwg = lwg; pwo = lwo;
        }
        k_mlp_in<<<dim3(32, 16), 256, 0, stream>>>(a_bf, pwv, pwg, g);
        k_mlp_out<<<dim3(32, 8), 256, 0, stream>>>(g, pwo, alpha_mlp + l, h, ssn);
    }
    k_norm<<<512, 256, 0, stream>>>(h, ss_hd, head_rms, a_bf);
    k_head<<<dim3(32, 4), 256, 0, stream>>>(a_bf, head_wb, head_scale, out);
}